// Round 16
// baseline (364.087 us; speedup 1.0000x reference)
//
#include <hip/hip_runtime.h>
#include <cstdint>
#include <cstddef>

typedef __bf16 bf16;
typedef __attribute__((ext_vector_type(8))) __bf16 bf16x8;
typedef __attribute__((ext_vector_type(4))) __bf16 bf16x4;
typedef __attribute__((ext_vector_type(4))) float f32x4;

constexpr int B_ = 2, S_ = 2048, H_ = 2048, NH_ = 16, NKV_ = 4, HD_ = 128;
constexpr float SCALE_ = 0.08838834764831845f;  // 1/sqrt(128)

#define GLDS16(g, l)                                                        \
  __builtin_amdgcn_global_load_lds(                                         \
      (const __attribute__((address_space(1))) void*)(g),                   \
      (__attribute__((address_space(3))) void*)(l), 16, 0, 0)

#define VMCNT0 asm volatile("s_waitcnt vmcnt(0)" ::: "memory")
#define BAR __builtin_amdgcn_s_barrier()

__device__ inline void nt_store4(float* p, f32x4 v) {
  __builtin_nontemporal_store(v, (f32x4*)p);
}

// ---------------- fused fp32 -> bf16 convert (all 5 tensors) ----------------
__global__ void cvt_all(const float* __restrict__ hs, const float* __restrict__ wq,
                        const float* __restrict__ wk, const float* __restrict__ wv,
                        const float* __restrict__ wo, bf16* __restrict__ xb,
                        bf16* __restrict__ w3b, bf16* __restrict__ wob) {
  const int stride = gridDim.x * blockDim.x;
  for (int i = blockIdx.x * blockDim.x + threadIdx.x; i < 4718592; i += stride) {
    const float4* s; bf16x4* d; int j;
    if (i < 2097152)      { s = (const float4*)hs; d = (bf16x4*)xb;            j = i; }
    else if (i < 3145728) { s = (const float4*)wq; d = (bf16x4*)w3b;           j = i - 2097152; }
    else if (i < 3407872) { s = (const float4*)wk; d = (bf16x4*)w3b + 1048576; j = i - 3145728; }
    else if (i < 3670016) { s = (const float4*)wv; d = (bf16x4*)w3b + 1310720; j = i - 3407872; }
    else                  { s = (const float4*)wo; d = (bf16x4*)wob;           j = i - 3670016; }
    float4 v = s[j];
    bf16x4 o;
    o[0] = (bf16)v.x; o[1] = (bf16)v.y; o[2] = (bf16)v.z; o[3] = (bf16)v.w;
    d[j] = o;
  }
}

// ---------------- bf16 GEMM  C[m][n] = sum_k A[m][k]*Bm[n][k] ----------------
// m97-exact structure: 128x128 tile, 4 waves, BK=64, SINGLE-buffered 32KB LDS.
template <int EPI>
__global__ __launch_bounds__(256) void gemm_bt(const bf16* __restrict__ A,
                                               const bf16* __restrict__ Bm, int K,
                                               bf16* __restrict__ qb, bf16* __restrict__ kb,
                                               bf16* __restrict__ vtb, float* __restrict__ Cout) {
  __shared__ __align__(16) bf16 As[128 * 64];
  __shared__ __align__(16) bf16 Bs[128 * 64];
  const int tid = threadIdx.x;
  const int lane = tid & 63;
  const int wid = tid >> 6;
  const int fid = blockIdx.y * 32 + blockIdx.x;
  const int nwg = gridDim.y * 32;
  const int swz = (fid & 7) * (nwg >> 3) + (fid >> 3);
  const int m0 = (swz & 31) * 128;
  const int n0 = (swz >> 5) * 128;
  const int wm = (wid >> 1) * 64, wn = (wid & 1) * 64;
  const int r = lane & 15, g = lane >> 4;
  f32x4 acc[4][4] = {};

#pragma unroll 1
  for (int kt = 0; kt < K; kt += 64) {
    __syncthreads();
#pragma unroll
    for (int i = 0; i < 4; ++i) {
      int cb = wid * 256 + i * 64;
      int c64 = cb + lane;
      int row = c64 >> 3, cs = (c64 & 7) ^ (row & 7);
      GLDS16(A + (size_t)(m0 + row) * K + kt + cs * 8, As + cb * 8);
      GLDS16(Bm + (size_t)(n0 + row) * K + kt + cs * 8, Bs + cb * 8);
    }
    VMCNT0;
    __syncthreads();
#pragma unroll
    for (int ks = 0; ks < 2; ++ks) {
      bf16x8 af[4], bfr[4];
#pragma unroll
      for (int fm = 0; fm < 4; ++fm)
        af[fm] = *(const bf16x8*)(As + (wm + fm * 16 + r) * 64 + (((ks * 4 + g) ^ (r & 7)) << 3));
#pragma unroll
      for (int fn = 0; fn < 4; ++fn)
        bfr[fn] = *(const bf16x8*)(Bs + (wn + fn * 16 + r) * 64 + (((ks * 4 + g) ^ (r & 7)) << 3));
#pragma unroll
      for (int fm = 0; fm < 4; ++fm)
#pragma unroll
        for (int fn = 0; fn < 4; ++fn)
          acc[fm][fn] = __builtin_amdgcn_mfma_f32_16x16x32_bf16(af[fm], bfr[fn], acc[fm][fn], 0, 0, 0);
    }
  }

#pragma unroll
  for (int fm = 0; fm < 4; ++fm)
#pragma unroll
    for (int fn = 0; fn < 4; ++fn)
#pragma unroll
      for (int rr = 0; rr < 4; ++rr) {
        int mm = m0 + wm + fm * 16 + g * 4 + rr;
        int nn = n0 + wn + fn * 16 + r;
        float v = acc[fm][fn][rr];
        if (EPI == 1) {
          Cout[(size_t)mm * 2048 + nn] = v;
        } else {
          int b = mm >> 11, s = mm & (S_ - 1);
          int d = nn & 127;
          if (nn < 2048) {
            int hh = nn >> 7;
            qb[(((size_t)b * NH_ + hh) * S_ + s) * HD_ + d] = (bf16)v;
          } else if (nn < 2560) {
            int hh = (nn - 2048) >> 7;
            kb[(((size_t)b * NKV_ + hh) * S_ + s) * HD_ + d] = (bf16)v;
          } else {
            int hh = (nn - 2560) >> 7;
            vtb[(((size_t)b * NKV_ + hh) * HD_ + d) * S_ + s] = (bf16)v;  // V transposed
          }
        }
      }
}

// ---------------- RoPE on K only (in-place, bf16, vectorized) ----------------
__global__ void rope_k_kernel(bf16* __restrict__ kb, const float* __restrict__ cosp,
                              const float* __restrict__ sinp) {
  const int NK = B_ * NKV_ * S_;  // 16384 k rows
  int t = blockIdx.x * blockDim.x + threadIdx.x;
  if (t >= NK * 8) return;
  const int oct = t & 7, rid = t >> 3;
  bf16* base = kb + (size_t)rid * HD_;
  const int s = rid & (S_ - 1);
  const int b = rid >> 13;
  const int d = oct * 8;
  const float* cp = cosp + ((size_t)b * S_ + s) * HD_ + d;
  const float* sp = sinp + ((size_t)b * S_ + s) * HD_ + d;
  float4 c0 = *(const float4*)cp, c1 = *(const float4*)(cp + 4);
  float4 s0 = *(const float4*)sp, s1 = *(const float4*)(sp + 4);
  float cc[8] = {c0.x, c0.y, c0.z, c0.w, c1.x, c1.y, c1.z, c1.w};
  float ss[8] = {s0.x, s0.y, s0.z, s0.w, s1.x, s1.y, s1.z, s1.w};
  bf16x8 x1 = *(const bf16x8*)(base + d);
  bf16x8 x2 = *(const bf16x8*)(base + d + 64);
  bf16x8 o1, o2;
#pragma unroll
  for (int i = 0; i < 8; ++i) {
    float a = (float)x1[i], bb = (float)x2[i];
    o1[i] = (bf16)(a * cc[i] - bb * ss[i]);
    o2[i] = (bf16)(bb * cc[i] + a * ss[i]);
  }
  *(bf16x8*)(base + d) = o1;
  *(bf16x8*)(base + d + 64) = o2;
}

// ------------- fused causal attention: KBLK=128, kk-hoisted across heads ----
// 512 blocks x 256 threads; balanced decode (CU hosts complementary qt pair).
// 2 heads/block GQA share.  K fragments read ONCE per fn and fed to both
// heads' MFMAs (halves QK^T LDS reads — LDS bandwidth is the computed floor).
// 80KB single-buffered LDS, 2 blocks/CU.  SWAPPED QK^T; no-max softmax;
// fused Q-RoPE; nontemporal f32 prob stores.
__global__ __launch_bounds__(256, 2) void attn_kernel(const bf16* __restrict__ qb,
                                                      const bf16* __restrict__ kb,
                                                      const bf16* __restrict__ vtb,
                                                      const float* __restrict__ cosp,
                                                      const float* __restrict__ sinp,
                                                      bf16* __restrict__ aob,
                                                      float* __restrict__ attn_out) {
  __shared__ __align__(16) bf16 Ks[128 * 128];  // [k][d]
  __shared__ __align__(16) bf16 Vs[128 * 128];  // [d][k]
  __shared__ __align__(16) bf16 Ps[64 * 128];   // [q][k], wave-private rows
  const int x7 = blockIdx.x & 7;
  const int k = blockIdx.x >> 3;             // 0..63
  const int qt = (k < 32) ? (31 - k) : (k - 32);
  const int g2 = x7 + ((k >> 5) << 3);       // group 0..15
  const int b = g2 >> 3;
  const int kh = (g2 >> 1) & 3;
  const int hp = g2 & 1;
  const int h0 = kh * 4 + hp * 2;            // heads h0, h0+1 share K/V of kh
  const int q0 = qt * 64;
  const int nt = (qt + 2) >> 1;              // 128-wide k tiles
  const int tid = threadIdx.x, lane = tid & 63, wid = tid >> 6;
  const int r = lane & 15, g = lane >> 4;

  const bf16* kbase = kb + ((size_t)b * NKV_ + kh) * S_ * HD_;
  const bf16* vbase = vtb + ((size_t)b * NKV_ + kh) * (size_t)HD_ * S_;
  size_t arow0[2];
#pragma unroll
  for (int hh = 0; hh < 2; ++hh)
    arow0[hh] = ((size_t)(b * NH_ + h0 + hh) * S_ + q0) * S_;

  auto stageK = [&](int kt) {
#pragma unroll
    for (int i = 0; i < 8; ++i) {
      int base = i * 256 + wid * 64;
      int idx = base + lane;
      int row = idx >> 4, ch = (idx & 15) ^ (row & 15);
      GLDS16(kbase + (size_t)(kt * 128 + row) * HD_ + ch * 8, Ks + base * 8);
    }
  };
  auto stageV = [&](int kt) {
#pragma unroll
    for (int i = 0; i < 8; ++i) {
      int base = i * 256 + wid * 64;
      int idx = base + lane;
      int row = idx >> 4, ch = (idx & 15) ^ (row & 15);
      GLDS16(vbase + (size_t)row * S_ + kt * 128 + ch * 8, Vs + base * 8);
    }
  };

  // ---- Q fragments with fused RoPE, both heads (shared cos/sin loads) ----
  bf16x8 qreg[2][4];
  {
    const int srow = q0 + wid * 16 + r;
    const float* cp = cosp + ((size_t)b * S_ + srow) * HD_;
    const float* sp = sinp + ((size_t)b * S_ + srow) * HD_;
    float cc[2][8], ss[2][8];
#pragma unroll
    for (int hf = 0; hf < 2; ++hf) {
      const int d0 = hf * 32 + g * 8;
      float4 ca = *(const float4*)(cp + d0), cb2 = *(const float4*)(cp + d0 + 4);
      float4 sa = *(const float4*)(sp + d0), sb2 = *(const float4*)(sp + d0 + 4);
      cc[hf][0] = ca.x; cc[hf][1] = ca.y; cc[hf][2] = ca.z; cc[hf][3] = ca.w;
      cc[hf][4] = cb2.x; cc[hf][5] = cb2.y; cc[hf][6] = cb2.z; cc[hf][7] = cb2.w;
      ss[hf][0] = sa.x; ss[hf][1] = sa.y; ss[hf][2] = sa.z; ss[hf][3] = sa.w;
      ss[hf][4] = sb2.x; ss[hf][5] = sb2.y; ss[hf][6] = sb2.z; ss[hf][7] = sb2.w;
    }
#pragma unroll
    for (int hh = 0; hh < 2; ++hh) {
      const bf16* qsrc = qb + ((size_t)(b * NH_ + h0 + hh) * S_ + q0) * HD_;
#pragma unroll
      for (int ks = 0; ks < 4; ++ks)
        qreg[hh][ks] = *(const bf16x8*)(qsrc + (wid * 16 + r) * HD_ + ks * 32 + g * 8);
#pragma unroll
      for (int hf = 0; hf < 2; ++hf) {
        bf16x8 lo = qreg[hh][hf], hi = qreg[hh][hf + 2];
#pragma unroll
        for (int i = 0; i < 8; ++i) {
          float a = (float)lo[i], bb = (float)hi[i];
          qreg[hh][hf][i] = (bf16)(a * cc[hf][i] - bb * ss[hf][i]);
          qreg[hh][hf + 2][i] = (bf16)(bb * cc[hf][i] + a * ss[hf][i]);
        }
      }
    }
  }

  // ---- pass 1: row sums for both heads (kk read once, fed to both) ----
  float lsum[2] = {0.f, 0.f};
#pragma unroll 1
  for (int kt = 0; kt < nt; ++kt) {
    __syncthreads();
    stageK(kt);
    VMCNT0;
    __syncthreads();
    const bool last = (kt == nt - 1);
    const int k0 = kt * 128;
    f32x4 sacc[2][8] = {};
    __builtin_amdgcn_s_setprio(1);
#pragma unroll
    for (int fn = 0; fn < 8; ++fn) {
      bf16x8 kk[4];
#pragma unroll
      for (int ks = 0; ks < 4; ++ks)
        kk[ks] = *(const bf16x8*)(Ks + (fn * 16 + r) * 128 + (((ks * 4 + g) ^ r) << 3));
#pragma unroll
      for (int hh = 0; hh < 2; ++hh)
#pragma unroll
        for (int ks = 0; ks < 4; ++ks)
          sacc[hh][fn] = __builtin_amdgcn_mfma_f32_16x16x32_bf16(kk[ks], qreg[hh][ks], sacc[hh][fn], 0, 0, 0);
    }
    __builtin_amdgcn_s_setprio(0);
#pragma unroll
    for (int hh = 0; hh < 2; ++hh) {
      float ts = 0.f;
      if (last) {
#pragma unroll
        for (int fn = 0; fn < 8; ++fn)
#pragma unroll
          for (int rr = 0; rr < 4; ++rr) {
            bool msk = (k0 + fn * 16 + g * 4 + rr) > (q0 + wid * 16 + r);
            ts += msk ? 0.f : __expf(sacc[hh][fn][rr] * SCALE_);
          }
      } else {
#pragma unroll
        for (int fn = 0; fn < 8; ++fn)
#pragma unroll
          for (int rr = 0; rr < 4; ++rr) ts += __expf(sacc[hh][fn][rr] * SCALE_);
      }
      ts += __shfl_xor(ts, 16);
      ts += __shfl_xor(ts, 32);
      lsum[hh] += ts;
    }
  }
  float rl[2] = {1.0f / lsum[0], 1.0f / lsum[1]};

  // ---- pass 2: probs (nontemporal f32) + PV; kk hoisted across heads ----
  f32x4 oacc[2][8] = {};
#pragma unroll 1
  for (int kt = 0; kt < nt; ++kt) {
    __syncthreads();
    stageK(kt);
    stageV(kt);
    VMCNT0;
    __syncthreads();
    const int k0 = kt * 128;
    const bool last = (kt == nt - 1);
    f32x4 sacc[2][8] = {};
    __builtin_amdgcn_s_setprio(1);
#pragma unroll
    for (int fn = 0; fn < 8; ++fn) {
      bf16x8 kk[4];
#pragma unroll
      for (int ks = 0; ks < 4; ++ks)
        kk[ks] = *(const bf16x8*)(Ks + (fn * 16 + r) * 128 + (((ks * 4 + g) ^ r) << 3));
#pragma unroll
      for (int hh = 0; hh < 2; ++hh)
#pragma unroll
        for (int ks = 0; ks < 4; ++ks)
          sacc[hh][fn] = __builtin_amdgcn_mfma_f32_16x16x32_bf16(kk[ks], qreg[hh][ks], sacc[hh][fn], 0, 0, 0);
    }
    __builtin_amdgcn_s_setprio(0);
#pragma unroll
    for (int hh = 0; hh < 2; ++hh) {
      const int prow = (wid * 16 + r) * 128;
#pragma unroll
      for (int fn = 0; fn < 8; ++fn) {
        f32x4 pv4;
        bf16x4 pk;
#pragma unroll
        for (int rr = 0; rr < 4; ++rr) {
          bool msk = last && ((k0 + fn * 16 + g * 4 + rr) > (q0 + wid * 16 + r));
          float f = msk ? 0.f : __expf(sacc[hh][fn][rr] * SCALE_) * rl[hh];
          pv4[rr] = f;
          pk[rr] = (bf16)f;
        }
        nt_store4(attn_out + arow0[hh] + (size_t)(wid * 16 + r) * S_ + k0 + fn * 16 + g * 4, pv4);
        *(bf16x4*)(&Ps[prow + ((((fn << 1) | (g >> 1)) ^ r) << 3) + ((g & 1) << 2)]) = pk;
      }
      // PV (Ps rows wave-private; per-wave DS ordering handles RAW)
      __builtin_amdgcn_s_setprio(1);
#pragma unroll
      for (int ks = 0; ks < 4; ++ks) {
        bf16x8 pa = *(const bf16x8*)(&Ps[prow + (((ks * 4 + g) ^ r) << 3)]);
#pragma unroll
        for (int fn = 0; fn < 8; ++fn) {
          bf16x8 vv = *(const bf16x8*)(Vs + (fn * 16 + r) * 128 + (((ks * 4 + g) ^ r) << 3));
          oacc[hh][fn] = __builtin_amdgcn_mfma_f32_16x16x32_bf16(pa, vv, oacc[hh][fn], 0, 0, 0);
        }
      }
      __builtin_amdgcn_s_setprio(0);
    }
  }

  // O tiles -> pre-projection buffer (b, s, h*128+d)
#pragma unroll
  for (int hh = 0; hh < 2; ++hh)
#pragma unroll
    for (int fn = 0; fn < 8; ++fn)
#pragma unroll
      for (int rr = 0; rr < 4; ++rr) {
        int q = q0 + wid * 16 + g * 4 + rr;
        aob[((size_t)b * S_ + q) * 2048 + (h0 + hh) * HD_ + fn * 16 + r] = (bf16)oacc[hh][fn][rr];
      }

  // trailing zero tiles (cols >= nt*128), both heads
  const int z0 = 2 * nt;
#pragma unroll 1
  for (int zi = 0; zi < 2 * (32 - z0); ++zi) {
    int hh = (zi >= 32 - z0) ? 1 : 0;
    int ktz = z0 + (hh ? zi - (32 - z0) : zi);
    float* zdst = attn_out + arow0[hh] + ktz * 64;
    f32x4 zv = {0.f, 0.f, 0.f, 0.f};
#pragma unroll
    for (int i = 0; i < 4; ++i) {
      int idx = i * 256 + tid;
      nt_store4(zdst + (size_t)(idx >> 4) * S_ + (idx & 15) * 4, zv);
    }
  }
}

// ---------------- launch ----------------
extern "C" void kernel_launch(void* const* d_in, const int* in_sizes, int n_in,
                              void* d_out, int out_size, void* d_ws, size_t ws_size,
                              hipStream_t stream) {
  const float* hidden = (const float*)d_in[0];
  const float* cosp = (const float*)d_in[1];
  const float* sinp = (const float*)d_in[2];
  const float* wq = (const float*)d_in[4];
  const float* wk = (const float*)d_in[5];
  const float* wv = (const float*)d_in[6];
  const float* wo = (const float*)d_in[7];
  float* out = (float*)d_out;
  float* attn = out + (size_t)B_ * S_ * H_;

  char* ws = (char*)d_ws;
  bf16* xb  = (bf16*)(ws);                          // [4096][2048]
  bf16* w3b = (bf16*)(ws + (16ull << 20));          // [3072][2048] (wq|wk|wv)
  bf16* wob = (bf16*)(ws + (28ull << 20));          // [2048][2048]
  bf16* qb  = (bf16*)(ws + (36ull << 20));          // [B][NH][S][HD]
  bf16* kb  = (bf16*)(ws + (52ull << 20));          // [B][NKV][S][HD]
  bf16* vtb = (bf16*)(ws + (56ull << 20));          // [B][NKV][HD][S]
  bf16* aob = (bf16*)(ws + (60ull << 20));          // [B][S][2048]

  cvt_all<<<2048, 256, 0, stream>>>(hidden, wq, wk, wv, wo, xb, w3b, wob);
  gemm_bt<0><<<dim3(32, 24), 256, 0, stream>>>(xb, w3b, 2048, qb, kb, vtb, nullptr);
  rope_k_kernel<<<512, 256, 0, stream>>>(kb, cosp, sinp);
  attn_kernel<<<512, 256, 0, stream>>>(qb, kb, vtb, cosp, sinp, aob, attn);
  gemm_bt<1><<<dim3(32, 16), 256, 0, stream>>>(aob, wob, 2048, nullptr, nullptr, nullptr, out);
}

// Round 17
// 331.488 us; speedup vs baseline: 1.0983x; 1.0983x over previous
//
#include <hip/hip_runtime.h>
#include <cstdint>
#include <cstddef>

typedef __bf16 bf16;
typedef __attribute__((ext_vector_type(8))) __bf16 bf16x8;
typedef __attribute__((ext_vector_type(4))) __bf16 bf16x4;
typedef __attribute__((ext_vector_type(4))) float f32x4;

constexpr int B_ = 2, S_ = 2048, H_ = 2048, NH_ = 16, NKV_ = 4, HD_ = 128;
constexpr float SCALE_ = 0.08838834764831845f;  // 1/sqrt(128)

#define GLDS16(g, l)                                                        \
  __builtin_amdgcn_global_load_lds(                                         \
      (const __attribute__((address_space(1))) void*)(g),                   \
      (__attribute__((address_space(3))) void*)(l), 16, 0, 0)

#define VMCNT0 asm volatile("s_waitcnt vmcnt(0)" ::: "memory")
#define BAR __builtin_amdgcn_s_barrier()

__device__ inline void nt_store4(float* p, f32x4 v) {
  __builtin_nontemporal_store(v, (f32x4*)p);
}

// ---------------- fused fp32 -> bf16 convert (all 5 tensors) ----------------
__global__ void cvt_all(const float* __restrict__ hs, const float* __restrict__ wq,
                        const float* __restrict__ wk, const float* __restrict__ wv,
                        const float* __restrict__ wo, bf16* __restrict__ xb,
                        bf16* __restrict__ w3b, bf16* __restrict__ wob) {
  const int stride = gridDim.x * blockDim.x;
  for (int i = blockIdx.x * blockDim.x + threadIdx.x; i < 4718592; i += stride) {
    const float4* s; bf16x4* d; int j;
    if (i < 2097152)      { s = (const float4*)hs; d = (bf16x4*)xb;            j = i; }
    else if (i < 3145728) { s = (const float4*)wq; d = (bf16x4*)w3b;           j = i - 2097152; }
    else if (i < 3407872) { s = (const float4*)wk; d = (bf16x4*)w3b + 1048576; j = i - 3145728; }
    else if (i < 3670016) { s = (const float4*)wv; d = (bf16x4*)w3b + 1310720; j = i - 3407872; }
    else                  { s = (const float4*)wo; d = (bf16x4*)wob;           j = i - 3670016; }
    float4 v = s[j];
    bf16x4 o;
    o[0] = (bf16)v.x; o[1] = (bf16)v.y; o[2] = (bf16)v.z; o[3] = (bf16)v.w;
    d[j] = o;
  }
}

// ---------------- bf16 GEMM  C[m][n] = sum_k A[m][k]*Bm[n][k] ----------------
// m97-exact structure: 128x128 tile, 4 waves, BK=64, SINGLE-buffered 32KB LDS.
template <int EPI>
__global__ __launch_bounds__(256) void gemm_bt(const bf16* __restrict__ A,
                                               const bf16* __restrict__ Bm, int K,
                                               bf16* __restrict__ qb, bf16* __restrict__ kb,
                                               bf16* __restrict__ vtb, float* __restrict__ Cout) {
  __shared__ __align__(16) bf16 As[128 * 64];
  __shared__ __align__(16) bf16 Bs[128 * 64];
  const int tid = threadIdx.x;
  const int lane = tid & 63;
  const int wid = tid >> 6;
  const int fid = blockIdx.y * 32 + blockIdx.x;
  const int nwg = gridDim.y * 32;
  const int swz = (fid & 7) * (nwg >> 3) + (fid >> 3);
  const int m0 = (swz & 31) * 128;
  const int n0 = (swz >> 5) * 128;
  const int wm = (wid >> 1) * 64, wn = (wid & 1) * 64;
  const int r = lane & 15, g = lane >> 4;
  f32x4 acc[4][4] = {};

#pragma unroll 1
  for (int kt = 0; kt < K; kt += 64) {
    __syncthreads();
#pragma unroll
    for (int i = 0; i < 4; ++i) {
      int cb = wid * 256 + i * 64;
      int c64 = cb + lane;
      int row = c64 >> 3, cs = (c64 & 7) ^ (row & 7);
      GLDS16(A + (size_t)(m0 + row) * K + kt + cs * 8, As + cb * 8);
      GLDS16(Bm + (size_t)(n0 + row) * K + kt + cs * 8, Bs + cb * 8);
    }
    VMCNT0;
    __syncthreads();
#pragma unroll
    for (int ks = 0; ks < 2; ++ks) {
      bf16x8 af[4], bfr[4];
#pragma unroll
      for (int fm = 0; fm < 4; ++fm)
        af[fm] = *(const bf16x8*)(As + (wm + fm * 16 + r) * 64 + (((ks * 4 + g) ^ (r & 7)) << 3));
#pragma unroll
      for (int fn = 0; fn < 4; ++fn)
        bfr[fn] = *(const bf16x8*)(Bs + (wn + fn * 16 + r) * 64 + (((ks * 4 + g) ^ (r & 7)) << 3));
#pragma unroll
      for (int fm = 0; fm < 4; ++fm)
#pragma unroll
        for (int fn = 0; fn < 4; ++fn)
          acc[fm][fn] = __builtin_amdgcn_mfma_f32_16x16x32_bf16(af[fm], bfr[fn], acc[fm][fn], 0, 0, 0);
    }
  }

#pragma unroll
  for (int fm = 0; fm < 4; ++fm)
#pragma unroll
    for (int fn = 0; fn < 4; ++fn)
#pragma unroll
      for (int rr = 0; rr < 4; ++rr) {
        int mm = m0 + wm + fm * 16 + g * 4 + rr;
        int nn = n0 + wn + fn * 16 + r;
        float v = acc[fm][fn][rr];
        if (EPI == 1) {
          Cout[(size_t)mm * 2048 + nn] = v;
        } else {
          int b = mm >> 11, s = mm & (S_ - 1);
          int d = nn & 127;
          if (nn < 2048) {
            int hh = nn >> 7;
            qb[(((size_t)b * NH_ + hh) * S_ + s) * HD_ + d] = (bf16)v;
          } else if (nn < 2560) {
            int hh = (nn - 2048) >> 7;
            kb[(((size_t)b * NKV_ + hh) * S_ + s) * HD_ + d] = (bf16)v;
          } else {
            int hh = (nn - 2560) >> 7;
            vtb[(((size_t)b * NKV_ + hh) * HD_ + d) * S_ + s] = (bf16)v;  // V transposed
          }
        }
      }
}

// ---------------- RoPE on K only (in-place, bf16, vectorized) ----------------
__global__ void rope_k_kernel(bf16* __restrict__ kb, const float* __restrict__ cosp,
                              const float* __restrict__ sinp) {
  const int NK = B_ * NKV_ * S_;  // 16384 k rows
  int t = blockIdx.x * blockDim.x + threadIdx.x;
  if (t >= NK * 8) return;
  const int oct = t & 7, rid = t >> 3;
  bf16* base = kb + (size_t)rid * HD_;
  const int s = rid & (S_ - 1);
  const int b = rid >> 13;
  const int d = oct * 8;
  const float* cp = cosp + ((size_t)b * S_ + s) * HD_ + d;
  const float* sp = sinp + ((size_t)b * S_ + s) * HD_ + d;
  float4 c0 = *(const float4*)cp, c1 = *(const float4*)(cp + 4);
  float4 s0 = *(const float4*)sp, s1 = *(const float4*)(sp + 4);
  float cc[8] = {c0.x, c0.y, c0.z, c0.w, c1.x, c1.y, c1.z, c1.w};
  float ss[8] = {s0.x, s0.y, s0.z, s0.w, s1.x, s1.y, s1.z, s1.w};
  bf16x8 x1 = *(const bf16x8*)(base + d);
  bf16x8 x2 = *(const bf16x8*)(base + d + 64);
  bf16x8 o1, o2;
#pragma unroll
  for (int i = 0; i < 8; ++i) {
    float a = (float)x1[i], bb = (float)x2[i];
    o1[i] = (bf16)(a * cc[i] - bb * ss[i]);
    o2[i] = (bf16)(bb * cc[i] + a * ss[i]);
  }
  *(bf16x8*)(base + d) = o1;
  *(bf16x8*)(base + d + 64) = o2;
}

// ------------- fused causal attention: KBLK=128 (half the visits) -----------
// 512 blocks x 256 threads; balanced decode (CU hosts complementary qt pair,
// visits/CU-pair constant at 17/pass).  2 heads/block GQA share.  K/V/Ps in
// 80KB single-buffered LDS (m97-style serial stage), 2 blocks/CU.  SWAPPED
// QK^T; no-max softmax; fused Q-RoPE; nontemporal f32 prob stores.  Diagonal
// 128-tile writes its own zero half; remaining zeros trail.
__global__ __launch_bounds__(256, 2) void attn_kernel(const bf16* __restrict__ qb,
                                                      const bf16* __restrict__ kb,
                                                      const bf16* __restrict__ vtb,
                                                      const float* __restrict__ cosp,
                                                      const float* __restrict__ sinp,
                                                      bf16* __restrict__ aob,
                                                      float* __restrict__ attn_out) {
  __shared__ __align__(16) bf16 Ks[128 * 128];  // [k][d]
  __shared__ __align__(16) bf16 Vs[128 * 128];  // [d][k]
  __shared__ __align__(16) bf16 Ps[64 * 128];   // [q][k], wave-private rows
  const int x7 = blockIdx.x & 7;
  const int k = blockIdx.x >> 3;             // 0..63
  const int qt = (k < 32) ? (31 - k) : (k - 32);
  const int g2 = x7 + ((k >> 5) << 3);       // group 0..15
  const int b = g2 >> 3;
  const int kh = (g2 >> 1) & 3;
  const int hp = g2 & 1;
  const int h0 = kh * 4 + hp * 2;            // heads h0, h0+1 share K/V of kh
  const int q0 = qt * 64;
  const int nt = (qt + 2) >> 1;              // 128-wide k tiles
  const int tid = threadIdx.x, lane = tid & 63, wid = tid >> 6;
  const int r = lane & 15, g = lane >> 4;

  const bf16* kbase = kb + ((size_t)b * NKV_ + kh) * S_ * HD_;
  const bf16* vbase = vtb + ((size_t)b * NKV_ + kh) * (size_t)HD_ * S_;
  size_t arow0[2];
#pragma unroll
  for (int hh = 0; hh < 2; ++hh)
    arow0[hh] = ((size_t)(b * NH_ + h0 + hh) * S_ + q0) * S_;

  auto stageK = [&](int kt) {
#pragma unroll
    for (int i = 0; i < 8; ++i) {
      int base = i * 256 + wid * 64;
      int idx = base + lane;
      int row = idx >> 4, ch = (idx & 15) ^ (row & 15);
      GLDS16(kbase + (size_t)(kt * 128 + row) * HD_ + ch * 8, Ks + base * 8);
    }
  };
  auto stageV = [&](int kt) {
#pragma unroll
    for (int i = 0; i < 8; ++i) {
      int base = i * 256 + wid * 64;
      int idx = base + lane;
      int row = idx >> 4, ch = (idx & 15) ^ (row & 15);
      GLDS16(vbase + (size_t)row * S_ + kt * 128 + ch * 8, Vs + base * 8);
    }
  };

  // ---- Q fragments with fused RoPE, both heads (shared cos/sin loads) ----
  bf16x8 qreg[2][4];
  {
    const int srow = q0 + wid * 16 + r;
    const float* cp = cosp + ((size_t)b * S_ + srow) * HD_;
    const float* sp = sinp + ((size_t)b * S_ + srow) * HD_;
    float cc[2][8], ss[2][8];
#pragma unroll
    for (int hf = 0; hf < 2; ++hf) {
      const int d0 = hf * 32 + g * 8;
      float4 ca = *(const float4*)(cp + d0), cb2 = *(const float4*)(cp + d0 + 4);
      float4 sa = *(const float4*)(sp + d0), sb2 = *(const float4*)(sp + d0 + 4);
      cc[hf][0] = ca.x; cc[hf][1] = ca.y; cc[hf][2] = ca.z; cc[hf][3] = ca.w;
      cc[hf][4] = cb2.x; cc[hf][5] = cb2.y; cc[hf][6] = cb2.z; cc[hf][7] = cb2.w;
      ss[hf][0] = sa.x; ss[hf][1] = sa.y; ss[hf][2] = sa.z; ss[hf][3] = sa.w;
      ss[hf][4] = sb2.x; ss[hf][5] = sb2.y; ss[hf][6] = sb2.z; ss[hf][7] = sb2.w;
    }
#pragma unroll
    for (int hh = 0; hh < 2; ++hh) {
      const bf16* qsrc = qb + ((size_t)(b * NH_ + h0 + hh) * S_ + q0) * HD_;
#pragma unroll
      for (int ks = 0; ks < 4; ++ks)
        qreg[hh][ks] = *(const bf16x8*)(qsrc + (wid * 16 + r) * HD_ + ks * 32 + g * 8);
#pragma unroll
      for (int hf = 0; hf < 2; ++hf) {
        bf16x8 lo = qreg[hh][hf], hi = qreg[hh][hf + 2];
#pragma unroll
        for (int i = 0; i < 8; ++i) {
          float a = (float)lo[i], bb = (float)hi[i];
          qreg[hh][hf][i] = (bf16)(a * cc[hf][i] - bb * ss[hf][i]);
          qreg[hh][hf + 2][i] = (bf16)(bb * cc[hf][i] + a * ss[hf][i]);
        }
      }
    }
  }

  // ---- pass 1: row sums for both heads ----
  float lsum[2] = {0.f, 0.f};
#pragma unroll 1
  for (int kt = 0; kt < nt; ++kt) {
    __syncthreads();
    stageK(kt);
    VMCNT0;
    __syncthreads();
    const bool last = (kt == nt - 1);
    const int k0 = kt * 128;
#pragma unroll
    for (int hh = 0; hh < 2; ++hh) {
      f32x4 sacc[8] = {};
      __builtin_amdgcn_s_setprio(1);
#pragma unroll
      for (int ks = 0; ks < 4; ++ks)
#pragma unroll
        for (int fn = 0; fn < 8; ++fn) {
          bf16x8 kk = *(const bf16x8*)(Ks + (fn * 16 + r) * 128 + (((ks * 4 + g) ^ r) << 3));
          sacc[fn] = __builtin_amdgcn_mfma_f32_16x16x32_bf16(kk, qreg[hh][ks], sacc[fn], 0, 0, 0);
        }
      __builtin_amdgcn_s_setprio(0);
      float ts = 0.f;
      if (last) {
#pragma unroll
        for (int fn = 0; fn < 8; ++fn)
#pragma unroll
          for (int rr = 0; rr < 4; ++rr) {
            bool msk = (k0 + fn * 16 + g * 4 + rr) > (q0 + wid * 16 + r);
            ts += msk ? 0.f : __expf(sacc[fn][rr] * SCALE_);
          }
      } else {
#pragma unroll
        for (int fn = 0; fn < 8; ++fn)
#pragma unroll
          for (int rr = 0; rr < 4; ++rr) ts += __expf(sacc[fn][rr] * SCALE_);
      }
      ts += __shfl_xor(ts, 16);
      ts += __shfl_xor(ts, 32);
      lsum[hh] += ts;
    }
  }
  float rl[2] = {1.0f / lsum[0], 1.0f / lsum[1]};

  // ---- pass 2: probs (nontemporal f32) + PV for both heads ----
  f32x4 oacc[2][8] = {};
#pragma unroll 1
  for (int kt = 0; kt < nt; ++kt) {
    __syncthreads();
    stageK(kt);
    stageV(kt);
    VMCNT0;
    __syncthreads();
    const int k0 = kt * 128;
    const bool last = (kt == nt - 1);
#pragma unroll
    for (int hh = 0; hh < 2; ++hh) {
      f32x4 sacc[8] = {};
      __builtin_amdgcn_s_setprio(1);
#pragma unroll
      for (int ks = 0; ks < 4; ++ks)
#pragma unroll
        for (int fn = 0; fn < 8; ++fn) {
          bf16x8 kk = *(const bf16x8*)(Ks + (fn * 16 + r) * 128 + (((ks * 4 + g) ^ r) << 3));
          sacc[fn] = __builtin_amdgcn_mfma_f32_16x16x32_bf16(kk, qreg[hh][ks], sacc[fn], 0, 0, 0);
        }
      __builtin_amdgcn_s_setprio(0);
      const int prow = (wid * 16 + r) * 128;
#pragma unroll
      for (int fn = 0; fn < 8; ++fn) {
        f32x4 pv4;
        bf16x4 pk;
#pragma unroll
        for (int rr = 0; rr < 4; ++rr) {
          bool msk = last && ((k0 + fn * 16 + g * 4 + rr) > (q0 + wid * 16 + r));
          float f = msk ? 0.f : __expf(sacc[fn][rr] * SCALE_) * rl[hh];
          pv4[rr] = f;
          pk[rr] = (bf16)f;
        }
        nt_store4(attn_out + arow0[hh] + (size_t)(wid * 16 + r) * S_ + k0 + fn * 16 + g * 4, pv4);
        *(bf16x4*)(&Ps[prow + ((((fn << 1) | (g >> 1)) ^ r) << 3) + ((g & 1) << 2)]) = pk;
      }
      // PV (Ps rows wave-private; per-wave DS ordering handles RAW)
      __builtin_amdgcn_s_setprio(1);
#pragma unroll
      for (int ks = 0; ks < 4; ++ks) {
        bf16x8 pa = *(const bf16x8*)(&Ps[prow + (((ks * 4 + g) ^ r) << 3)]);
#pragma unroll
        for (int fn = 0; fn < 8; ++fn) {
          bf16x8 vv = *(const bf16x8*)(Vs + (fn * 16 + r) * 128 + (((ks * 4 + g) ^ r) << 3));
          oacc[hh][fn] = __builtin_amdgcn_mfma_f32_16x16x32_bf16(pa, vv, oacc[hh][fn], 0, 0, 0);
        }
      }
      __builtin_amdgcn_s_setprio(0);
    }
  }

  // O tiles -> pre-projection buffer (b, s, h*128+d)
#pragma unroll
  for (int hh = 0; hh < 2; ++hh)
#pragma unroll
    for (int fn = 0; fn < 8; ++fn)
#pragma unroll
      for (int rr = 0; rr < 4; ++rr) {
        int q = q0 + wid * 16 + g * 4 + rr;
        aob[((size_t)b * S_ + q) * 2048 + (h0 + hh) * HD_ + fn * 16 + r] = (bf16)oacc[hh][fn][rr];
      }

  // trailing zero tiles (cols >= nt*128), both heads
  const int z0 = 2 * nt;
#pragma unroll 1
  for (int zi = 0; zi < 2 * (32 - z0); ++zi) {
    int hh = (zi >= 32 - z0) ? 1 : 0;
    int ktz = z0 + (hh ? zi - (32 - z0) : zi);
    float* zdst = attn_out + arow0[hh] + ktz * 64;
    f32x4 zv = {0.f, 0.f, 0.f, 0.f};
#pragma unroll
    for (int i = 0; i < 4; ++i) {
      int idx = i * 256 + tid;
      nt_store4(zdst + (size_t)(idx >> 4) * S_ + (idx & 15) * 4, zv);
    }
  }
}

// ---------------- launch ----------------
extern "C" void kernel_launch(void* const* d_in, const int* in_sizes, int n_in,
                              void* d_out, int out_size, void* d_ws, size_t ws_size,
                              hipStream_t stream) {
  const float* hidden = (const float*)d_in[0];
  const float* cosp = (const float*)d_in[1];
  const float* sinp = (const float*)d_in[2];
  const float* wq = (const float*)d_in[4];
  const float* wk = (const float*)d_in[5];
  const float* wv = (const float*)d_in[6];
  const float* wo = (const float*)d_in[7];
  float* out = (float*)d_out;
  float* attn = out + (size_t)B_ * S_ * H_;

  char* ws = (char*)d_ws;
  bf16* xb  = (bf16*)(ws);                          // [4096][2048]
  bf16* w3b = (bf16*)(ws + (16ull << 20));          // [3072][2048] (wq|wk|wv)
  bf16* wob = (bf16*)(ws + (28ull << 20));          // [2048][2048]
  bf16* qb  = (bf16*)(ws + (36ull << 20));          // [B][NH][S][HD]
  bf16* kb  = (bf16*)(ws + (52ull << 20));          // [B][NKV][S][HD]
  bf16* vtb = (bf16*)(ws + (56ull << 20));          // [B][NKV][HD][S]
  bf16* aob = (bf16*)(ws + (60ull << 20));          // [B][S][2048]

  cvt_all<<<2048, 256, 0, stream>>>(hidden, wq, wk, wv, wo, xb, w3b, wob);
  gemm_bt<0><<<dim3(32, 24), 256, 0, stream>>>(xb, w3b, 2048, qb, kb, vtb, nullptr);
  rope_k_kernel<<<512, 256, 0, stream>>>(kb, cosp, sinp);
  attn_kernel<<<512, 256, 0, stream>>>(qb, kb, vtb, cosp, sinp, aob, attn);
  gemm_bt<1><<<dim3(32, 16), 256, 0, stream>>>(aob, wob, 2048, nullptr, nullptr, nullptr, out);
}